// Round 1
// baseline (94.990 us; speedup 1.0000x reference)
//
#include <hip/hip_runtime.h>

#define N_PART 4096
#define RADIUS 0.1f
#define R2 0.01f
// (0.1 + 0.05*sqrt(3))^2 = 0.03482051, with margin:
#define PRE2 0.034830f
#define EPS_K 1e-12f
#define TJ 1024

__global__ __launch_bounds__(256) void convsp_kernel(
    const float* __restrict__ locs,    // [B,N,3]
    const float* __restrict__ data,    // [B,N,16]
    const float* __restrict__ density, // [B,N]
    const float* __restrict__ weight,  // [16,16,27]
    const float* __restrict__ bias,    // [16]
    float* __restrict__ out)           // [B,N,16]
{
    __shared__ float4 s_locs[TJ];

    const int tid  = threadIdx.x;
    const int b    = blockIdx.x >> 9;                       // 512 blocks per batch
    const int i    = ((blockIdx.x & 511) << 3) + (tid >> 5); // 8 particles per block
    const int lane = tid & 31;                               // 32 lanes per particle
    const int k    = lane;                                   // kernel-cell role in process phase

    const float* locs_b = locs    + (size_t)b * N_PART * 3;
    const float* data_b = data    + (size_t)b * N_PART * 16;
    const float* dens_b = density + (size_t)b * N_PART;

    const float lix = locs_b[i*3 + 0];
    const float liy = locs_b[i*3 + 1];
    const float liz = locs_b[i*3 + 2];

    // this lane's kernel-cell center (lanes 27..31 pushed to infinity -> never hit)
    float cx, cy, cz;
    {
        const int kk = (k < 27) ? k : 13;
        const float ox = (float)(kk / 9      - 1) * 0.05f;
        const float oy = (float)((kk / 3) % 3 - 1) * 0.05f;
        const float oz = (float)(kk % 3      - 1) * 0.05f;
        cx = lix + ox; cy = liy + oy; cz = liz + oz;
        if (k >= 27) cx = 1e9f;
    }

    float kv[16];
#pragma unroll
    for (int c = 0; c < 16; ++c) kv[c] = 0.f;

    for (int tb = 0; tb < N_PART; tb += TJ) {
        __syncthreads();
        {
            float* sf = (float*)s_locs;
            // pack [TJ][3] -> [TJ][4] (pad) for single b128 reads
            for (int idx = tid; idx < TJ * 3; idx += 256) {
                sf[idx + idx / 3] = locs_b[tb * 3 + idx];
            }
        }
        __syncthreads();

        for (int base = 0; base < TJ; base += 32) {
            // ---- scan phase: lane = candidate j offset, prefilter on particle distance
            const float4 lj = s_locs[base + lane];
            const float ddx = lix - lj.x, ddy = liy - lj.y, ddz = liz - lj.z;
            const float d2p = ddx*ddx + ddy*ddy + ddz*ddz;
            const unsigned long long m = __ballot(d2p < PRE2);
            unsigned int mh = (unsigned int)(m >> (tid & 32)); // this half's 32 bits

            // ---- process phase: lane = kernel cell k
            while (mh) {
                const int bit = __ffs(mh) - 1;
                mh &= (mh - 1);
                const int jj = base + bit;
                const float4 q = s_locs[jj];           // uniform per half -> broadcast
                const float dx = cx - q.x, dy = cy - q.y, dz = cz - q.z;
                const float d2 = dx*dx + dy*dy + dz*dz;
                if (d2 < R2) {
                    const float d = sqrtf(fmaxf(d2, EPS_K));
                    const float t = __builtin_fmaf(d, -10.f, 1.f); // 1 - d/R
                    const float w = t * t * t;
                    const int gj = tb + jj;
                    const float wd = w / dens_b[gj];
                    const float4* dp = (const float4*)(data_b + (size_t)gj * 16);
                    const float4 v0 = dp[0], v1 = dp[1], v2 = dp[2], v3 = dp[3];
                    kv[ 0] = fmaf(wd, v0.x, kv[ 0]);
                    kv[ 1] = fmaf(wd, v0.y, kv[ 1]);
                    kv[ 2] = fmaf(wd, v0.z, kv[ 2]);
                    kv[ 3] = fmaf(wd, v0.w, kv[ 3]);
                    kv[ 4] = fmaf(wd, v1.x, kv[ 4]);
                    kv[ 5] = fmaf(wd, v1.y, kv[ 5]);
                    kv[ 6] = fmaf(wd, v1.z, kv[ 6]);
                    kv[ 7] = fmaf(wd, v1.w, kv[ 7]);
                    kv[ 8] = fmaf(wd, v2.x, kv[ 8]);
                    kv[ 9] = fmaf(wd, v2.y, kv[ 9]);
                    kv[10] = fmaf(wd, v2.z, kv[10]);
                    kv[11] = fmaf(wd, v2.w, kv[11]);
                    kv[12] = fmaf(wd, v3.x, kv[12]);
                    kv[13] = fmaf(wd, v3.y, kv[13]);
                    kv[14] = fmaf(wd, v3.z, kv[14]);
                    kv[15] = fmaf(wd, v3.w, kv[15]);
                }
            }
        }
    }

    // ---- epilogue: val[o] = sum_c weight[o,c,k]*kv[c]; reduce over k (width-32 tree)
    const int kk = (k < 27) ? k : 26;   // idle lanes have kv==0, contribute 0
    float res = 0.f;
#pragma unroll
    for (int o = 0; o < 16; ++o) {
        float s = 0.f;
#pragma unroll
        for (int c = 0; c < 16; ++c)
            s = fmaf(weight[(o * 16 + c) * 27 + kk], kv[c], s);
#pragma unroll
        for (int d = 16; d >= 1; d >>= 1)
            s += __shfl_xor(s, d, 32);
        if (lane == o) res = s;
    }
    if (lane < 16) {
        out[((size_t)(b * N_PART + i)) * 16 + lane] = res + bias[lane];
    }
}

extern "C" void kernel_launch(void* const* d_in, const int* in_sizes, int n_in,
                              void* d_out, int out_size, void* d_ws, size_t ws_size,
                              hipStream_t stream) {
    const float* locs    = (const float*)d_in[0];
    const float* data    = (const float*)d_in[1];
    const float* density = (const float*)d_in[2];
    const float* weight  = (const float*)d_in[3];
    const float* bias    = (const float*)d_in[4];
    float* out = (float*)d_out;

    const int B = in_sizes[2] / N_PART;   // density is [B,N]
    dim3 grid(B * (N_PART / 8));
    dim3 block(256);
    convsp_kernel<<<grid, block, 0, stream>>>(locs, data, density, weight, bias, out);
}